// Round 1
// baseline (240.175 us; speedup 1.0000x reference)
//
#include <hip/hip_runtime.h>
#include <hip/hip_bf16.h>

#define TEMP_INV (1.0f / 0.07f)
#define LOG2E 1.4426950408889634f
#define LN2 0.6931471805599453f
#define NSPLIT 8

typedef __attribute__((ext_vector_type(4))) float f32x4;
typedef __attribute__((ext_vector_type(8))) short bf16x8;

__device__ __forceinline__ ushort f2bf(float x) {
  union { float f; unsigned u; } v; v.f = x;
  unsigned r = (v.u + 0x7fffu + ((v.u >> 16) & 1u)) >> 16;
  return (ushort)r;
}

// ---------------- Kernel 1: L2-normalize rows, write bf16 feats, cross dot ----
__global__ __launch_bounds__(256) void norm_kernel(
    const float* __restrict__ A, const float* __restrict__ P,
    ushort* __restrict__ F, float* __restrict__ cross, int B, int D) {
  const int row = blockIdx.x;
  const int t = threadIdx.x;
  const float4* a4 = reinterpret_cast<const float4*>(A + (size_t)row * D);
  const float4* p4 = reinterpret_cast<const float4*>(P + (size_t)row * D);
  const int n4 = D >> 2;
  float sa = 0.f, sp = 0.f, sx = 0.f;
  for (int i = t; i < n4; i += 256) {
    float4 av = a4[i], pv = p4[i];
    sa += av.x * av.x + av.y * av.y + av.z * av.z + av.w * av.w;
    sp += pv.x * pv.x + pv.y * pv.y + pv.z * pv.z + pv.w * pv.w;
    sx += av.x * pv.x + av.y * pv.y + av.z * pv.z + av.w * pv.w;
  }
#pragma unroll
  for (int off = 32; off; off >>= 1) {
    sa += __shfl_down(sa, off);
    sp += __shfl_down(sp, off);
    sx += __shfl_down(sx, off);
  }
  __shared__ float red[3][4];
  const int wid = t >> 6, lane = t & 63;
  if (lane == 0) { red[0][wid] = sa; red[1][wid] = sp; red[2][wid] = sx; }
  __syncthreads();
  sa = red[0][0] + red[0][1] + red[0][2] + red[0][3];
  sp = red[1][0] + red[1][1] + red[1][2] + red[1][3];
  sx = red[2][0] + red[2][1] + red[2][2] + red[2][3];
  const float ia = rsqrtf(sa), ip = rsqrtf(sp);
  ushort* fa = F + (size_t)row * D;
  ushort* fp = F + (size_t)(B + row) * D;
  for (int i = t; i < n4; i += 256) {
    float4 av = a4[i], pv = p4[i];
    ushort4 oa, op;
    oa.x = f2bf(av.x * ia); oa.y = f2bf(av.y * ia);
    oa.z = f2bf(av.z * ia); oa.w = f2bf(av.w * ia);
    op.x = f2bf(pv.x * ip); op.y = f2bf(pv.y * ip);
    op.z = f2bf(pv.z * ip); op.w = f2bf(pv.w * ip);
    reinterpret_cast<ushort4*>(fa)[i] = oa;
    reinterpret_cast<ushort4*>(fp)[i] = op;
  }
  if (t == 0) cross[row] = sx * ia * ip;
}

// ---------------- Kernel 2: fused Gram (F F^T / T) + online partial LSE ------
#define BM 128
#define BN 128
#define BK 64

__global__ __launch_bounds__(256, 2) void gram_lse_kernel(
    const ushort* __restrict__ F, float* __restrict__ part_m,
    float* __restrict__ part_l, int NN, int D, int chunkCols) {
  __shared__ ushort As[BM * BK];
  __shared__ ushort Bs[BN * BK];
  const int r0 = blockIdx.x * BM;
  const int c0 = blockIdx.y * chunkCols;
  const int t = threadIdx.x;
  const int lane = t & 63, w = t >> 6;
  const int lo = lane & 15, hi = lane >> 4;
  const int wr = w >> 1, wc = w & 1;

  // staging: thread t owns 16B chunks {t, t+256, t+512, t+768} of each tile
  int srow[4], skc[4], soff[4];
#pragma unroll
  for (int cc = 0; cc < 4; ++cc) {
    int c = t + 256 * cc;
    int row = c >> 3, kc = c & 7;
    srow[cc] = row; skc[cc] = kc;
    soff[cc] = row * BK + ((kc ^ (row & 7)) * 8);  // XOR-swizzled slot
  }

  // fragment read row bases (elements) + swizzled k-chunk offsets
  int iRowOff[4], jRowOff[4];
#pragma unroll
  for (int f = 0; f < 4; ++f) {
    iRowOff[f] = (wc * 64 + f * 16 + lo) * BK;
    jRowOff[f] = (wr * 64 + f * 16 + lo) * BK;
  }
  const int swz0 = ((0 + hi) ^ (lo & 7)) * 8;
  const int swz1 = ((4 + hi) ^ (lo & 7)) * 8;

  float m_st[4], l_st[4];
#pragma unroll
  for (int f = 0; f < 4; ++f) { m_st[f] = -3.0e38f; l_st[f] = 0.f; }

  const float scl = LOG2E * TEMP_INV;  // base-2 logit scale
  const f32x4 zero4 = {0.f, 0.f, 0.f, 0.f};
  const int nJT = chunkCols / BN;

  for (int jt = 0; jt < nJT; ++jt) {
    const int jbase = c0 + jt * BN;
    f32x4 acc[4][4];
#pragma unroll
    for (int a = 0; a < 4; ++a)
#pragma unroll
      for (int b = 0; b < 4; ++b) acc[a][b] = zero4;

    const ushort* aP[4];
    const ushort* bP[4];
#pragma unroll
    for (int cc = 0; cc < 4; ++cc) {
      aP[cc] = F + (size_t)(r0 + srow[cc]) * D + skc[cc] * 8;
      bP[cc] = F + (size_t)(jbase + srow[cc]) * D + skc[cc] * 8;
    }

    for (int ks = 0; ks < D; ks += BK) {
      bf16x8 ra[4], rb[4];
#pragma unroll
      for (int cc = 0; cc < 4; ++cc) {
        ra[cc] = *(const bf16x8*)(aP[cc]);
        rb[cc] = *(const bf16x8*)(bP[cc]);
        aP[cc] += BK; bP[cc] += BK;
      }
      __syncthreads();  // previous compute done reading LDS
#pragma unroll
      for (int cc = 0; cc < 4; ++cc) {
        *(bf16x8*)&As[soff[cc]] = ra[cc];
        *(bf16x8*)&Bs[soff[cc]] = rb[cc];
      }
      __syncthreads();  // tiles ready
#pragma unroll
      for (int kk = 0; kk < 2; ++kk) {
        const int sw = kk ? swz1 : swz0;
        bf16x8 fi[4], fj[4];
#pragma unroll
        for (int f = 0; f < 4; ++f) fi[f] = *(const bf16x8*)&As[iRowOff[f] + sw];
#pragma unroll
        for (int f = 0; f < 4; ++f) fj[f] = *(const bf16x8*)&Bs[jRowOff[f] + sw];
#pragma unroll
        for (int a = 0; a < 4; ++a)
#pragma unroll
          for (int b = 0; b < 4; ++b)
            acc[a][b] = __builtin_amdgcn_mfma_f32_16x16x32_bf16(
                fj[a], fi[b], acc[a][b], 0, 0, 0);
      }
    }

    // epilogue: online LSE update in base-2 space.
    // acc[mf][nf][rg]: row j = jbase + wr*64 + mf*16 + hi*4 + rg (MFMA M-side)
    //                  col i = r0 + wc*64 + nf*16 + lo           (MFMA N-side)
#pragma unroll
    for (int nf = 0; nf < 4; ++nf) {
      const int ig = r0 + wc * 64 + nf * 16 + lo;
      float vals[16];
      float tmax = -3.0e38f;
#pragma unroll
      for (int mf = 0; mf < 4; ++mf) {
#pragma unroll
        for (int rg = 0; rg < 4; ++rg) {
          const int jg = jbase + wr * 64 + mf * 16 + hi * 4 + rg;
          float v = (ig == jg) ? -1.0e9f : acc[mf][nf][rg] * scl;
          vals[mf * 4 + rg] = v;
          tmax = fmaxf(tmax, v);
        }
      }
      tmax = fmaxf(tmax, __shfl_xor(tmax, 16));
      tmax = fmaxf(tmax, __shfl_xor(tmax, 32));
      const float newm = fmaxf(m_st[nf], tmax);
      float ssum = 0.f;
#pragma unroll
      for (int q = 0; q < 16; ++q) ssum += exp2f(vals[q] - newm);
      ssum += __shfl_xor(ssum, 16);
      ssum += __shfl_xor(ssum, 32);
      l_st[nf] = l_st[nf] * exp2f(m_st[nf] - newm) + ssum;
      m_st[nf] = newm;
    }
  }

  if (hi == 0) {
    const int p = blockIdx.y * 2 + wr;
#pragma unroll
    for (int nf = 0; nf < 4; ++nf) {
      const int ig = r0 + wc * 64 + nf * 16 + lo;
      part_m[(size_t)p * NN + ig] = m_st[nf];
      part_l[(size_t)p * NN + ig] = l_st[nf];
    }
  }
}

// ---------------- Kernel 3: combine partials, final loss ---------------------
__global__ __launch_bounds__(1024) void finalize_kernel(
    const float* __restrict__ part_m, const float* __restrict__ part_l,
    const float* __restrict__ cross, const int* __restrict__ labels,
    float* __restrict__ out, int B, int nparts) {
  const int NN = 2 * B;
  const int t = threadIdx.x;
  float sum = 0.f, cnt = 0.f;
  for (int i = t; i < NN; i += 1024) {
    float M = -3.0e38f;
    for (int p = 0; p < nparts; ++p) M = fmaxf(M, part_m[(size_t)p * NN + i]);
    float L = 0.f;
    for (int p = 0; p < nparts; ++p)
      L += part_l[(size_t)p * NN + i] * exp2f(part_m[(size_t)p * NN + i] - M);
    const float lse = LN2 * (M + log2f(L));
    const float lab = (float)labels[i % B];
    sum += (lse - cross[i % B] * TEMP_INV) * lab;
    cnt += lab;
  }
#pragma unroll
  for (int off = 32; off; off >>= 1) {
    sum += __shfl_down(sum, off);
    cnt += __shfl_down(cnt, off);
  }
  __shared__ float rs[16], rc[16];
  const int wid = t >> 6, lane = t & 63;
  if (lane == 0) { rs[wid] = sum; rc[wid] = cnt; }
  __syncthreads();
  if (t == 0) {
    float S = 0.f, C = 0.f;
    for (int q = 0; q < 16; ++q) { S += rs[q]; C += rc[q]; }
    out[0] = (C > 0.f) ? S / C : 0.f;
  }
}

extern "C" void kernel_launch(void* const* d_in, const int* in_sizes, int n_in,
                              void* d_out, int out_size, void* d_ws, size_t ws_size,
                              hipStream_t stream) {
  const float* A = (const float*)d_in[0];
  const float* P = (const float*)d_in[1];
  const int* labels = (const int*)d_in[2];
  float* out = (float*)d_out;
  const int B = in_sizes[2];
  const int D = in_sizes[0] / B;
  const int NN = 2 * B;

  char* ws = (char*)d_ws;
  ushort* F = (ushort*)ws;
  size_t off = (size_t)NN * D * sizeof(ushort);
  off = (off + 255) & ~(size_t)255;
  float* cross = (float*)(ws + off);
  off += (size_t)B * sizeof(float);
  off = (off + 255) & ~(size_t)255;
  float* part_m = (float*)(ws + off);
  off += (size_t)2 * NSPLIT * NN * sizeof(float);
  off = (off + 255) & ~(size_t)255;
  float* part_l = (float*)(ws + off);

  norm_kernel<<<B, 256, 0, stream>>>(A, P, F, cross, B, D);
  dim3 g2(NN / BM, NSPLIT);
  gram_lse_kernel<<<g2, 256, 0, stream>>>(F, part_m, part_l, NN, D, NN / NSPLIT);
  finalize_kernel<<<1, 1024, 0, stream>>>(part_m, part_l, cross, labels, out, B,
                                          2 * NSPLIT);
}

// Round 2
// 155.237 us; speedup vs baseline: 1.5471x; 1.5471x over previous
//
#include <hip/hip_runtime.h>
#include <hip/hip_bf16.h>

#define TEMP_INV (1.0f / 0.07f)
#define LOG2E 1.4426950408889634f
#define LN2 0.6931471805599453f
#define NSPLIT 8

typedef __attribute__((ext_vector_type(4))) float f32x4;
typedef __attribute__((ext_vector_type(8))) short bf16x8;

__device__ __forceinline__ ushort f2bf(float x) {
  union { float f; unsigned u; } v; v.f = x;
  unsigned r = (v.u + 0x7fffu + ((v.u >> 16) & 1u)) >> 16;
  return (ushort)r;
}

__device__ __forceinline__ void gload16(const ushort* g, ushort* l) {
  __builtin_amdgcn_global_load_lds(
      (const __attribute__((address_space(1))) void*)g,
      (__attribute__((address_space(3))) void*)l, 16, 0, 0);
}

// ---------------- Kernel 1: L2-normalize rows, write bf16 feats, cross dot ----
__global__ __launch_bounds__(256) void norm_kernel(
    const float* __restrict__ A, const float* __restrict__ P,
    ushort* __restrict__ F, float* __restrict__ cross, int B, int D) {
  const int row = blockIdx.x;
  const int t = threadIdx.x;
  const float4* a4 = reinterpret_cast<const float4*>(A + (size_t)row * D);
  const float4* p4 = reinterpret_cast<const float4*>(P + (size_t)row * D);
  const int n4 = D >> 2;
  float sa = 0.f, sp = 0.f, sx = 0.f;
  for (int i = t; i < n4; i += 256) {
    float4 av = a4[i], pv = p4[i];
    sa += av.x * av.x + av.y * av.y + av.z * av.z + av.w * av.w;
    sp += pv.x * pv.x + pv.y * pv.y + pv.z * pv.z + pv.w * pv.w;
    sx += av.x * pv.x + av.y * pv.y + av.z * pv.z + av.w * pv.w;
  }
#pragma unroll
  for (int off = 32; off; off >>= 1) {
    sa += __shfl_down(sa, off);
    sp += __shfl_down(sp, off);
    sx += __shfl_down(sx, off);
  }
  __shared__ float red[3][4];
  const int wid = t >> 6, lane = t & 63;
  if (lane == 0) { red[0][wid] = sa; red[1][wid] = sp; red[2][wid] = sx; }
  __syncthreads();
  sa = red[0][0] + red[0][1] + red[0][2] + red[0][3];
  sp = red[1][0] + red[1][1] + red[1][2] + red[1][3];
  sx = red[2][0] + red[2][1] + red[2][2] + red[2][3];
  const float ia = rsqrtf(sa), ip = rsqrtf(sp);
  ushort* fa = F + (size_t)row * D;
  ushort* fp = F + (size_t)(B + row) * D;
  for (int i = t; i < n4; i += 256) {
    float4 av = a4[i], pv = p4[i];
    ushort4 oa, op;
    oa.x = f2bf(av.x * ia); oa.y = f2bf(av.y * ia);
    oa.z = f2bf(av.z * ia); oa.w = f2bf(av.w * ia);
    op.x = f2bf(pv.x * ip); op.y = f2bf(pv.y * ip);
    op.z = f2bf(pv.z * ip); op.w = f2bf(pv.w * ip);
    reinterpret_cast<ushort4*>(fa)[i] = oa;
    reinterpret_cast<ushort4*>(fp)[i] = op;
  }
  if (t == 0) cross[row] = sx * ia * ip;
}

// ---------------- Kernel 2: fused Gram (F F^T / T) + online partial LSE ------
// 256x256 tile, BK=32, triple-buffered LDS via global_load_lds (counted vmcnt).
// LDS tile layout (per 256x32 bf16 tile, 16KB): paired rows.
//   element (trow,k): lrow=trow>>1; cu=(trow&1)*4+(k>>3); c=cu^(lrow&7);
//   byte = lrow*128 + c*16 + (k&7)*2.  (granule = c mod 8 -> conflict-free)
#define BMI 256
#define BNJ 256
#define BK 32
#define KT_PER_JT 32  /* D/BK */
#define NJT 4         /* (NN/NSPLIT)/BNJ */
#define VTOT (NJT * KT_PER_JT)

__global__ __launch_bounds__(512, 2) void gram_lse_kernel(
    const ushort* __restrict__ F, float* __restrict__ part_m,
    float* __restrict__ part_l, int NN, int D) {
  __shared__ ushort lds[3][2][8192];  // [buf][A=0/B=1][16KB tile]
  const int r0 = blockIdx.x * BMI;              // i-rows (N-side, LSE state)
  const int c0 = blockIdx.y * (NN / NSPLIT);    // j-chunk base (M-side)
  const int t = threadIdx.x;
  const int lane = t & 63, w = t >> 6;
  const int lo = lane & 15, hi = lane >> 4;
  const int wr = w >> 2, wn = w & 3;  // wr: j-half(128), wn: i-quarter(64)

  // ---- staging: wave w stages segments w and w+8 of each tile (1KB each).
  // lane l -> lrow = seg*8 + (l>>3), swizzled chunk c = l&7;
  // cu = c ^ (l>>3); trow = seg*16 + (l>>3)*2 + (cu>>2); kc = cu&3.
  const int l3 = lane >> 3, l7 = lane & 7;
  const int cu = l7 ^ l3;
  const int sub = cu >> 2, kc = cu & 3;
  const int trow0 = w * 16 + l3 * 2 + sub;
  const int trow1 = (w + 8) * 16 + l3 * 2 + sub;
  const ushort* baseA0 = F + (size_t)(c0 + trow0) * D + kc * 8;
  const ushort* baseA1 = F + (size_t)(c0 + trow1) * D + kc * 8;
  const ushort* baseB0 = F + (size_t)(r0 + trow0) * D + kc * 8;
  const ushort* baseB1 = F + (size_t)(r0 + trow1) * D + kc * 8;
  const int dst0 = w * 512, dst1 = (w + 8) * 512;  // ushort offsets

  // ---- fragment read bases (byte offsets within a 16KB tile)
  // A frag mf: trow = wr*128 + mf*16 + lo, k-chunk hi.
  const int cA = (((lo & 1) << 2) | hi) ^ (lo >> 1);
  const int rdA = wr * 8192 + (lo >> 1) * 128 + cA * 16;  // + mf*1024
  const int rdB = wn * 4096 + (lo >> 1) * 128 + cA * 16;  // + nf*1024

  float m_st[4], l_st[4];
#pragma unroll
  for (int f = 0; f < 4; ++f) { m_st[f] = -3.0e38f; l_st[f] = 0.f; }
  const float scl = LOG2E * TEMP_INV;

  auto STAGE = [&](int u, int b) {
    const int jtc = u >> 5;
    const int ksc = (u & 31) * BK;
    const size_t ja = (size_t)jtc * BNJ * D + ksc;
    gload16(baseA0 + ja, &lds[b][0][dst0]);
    gload16(baseA1 + ja, &lds[b][0][dst1]);
    gload16(baseB0 + ksc, &lds[b][1][dst0]);
    gload16(baseB1 + ksc, &lds[b][1][dst1]);
  };

  STAGE(0, 0);
  STAGE(1, 1);
  int bcur = 0;

  for (int jt = 0; jt < NJT; ++jt) {
    f32x4 acc[8][4];
#pragma unroll
    for (int a = 0; a < 8; ++a)
#pragma unroll
      for (int b = 0; b < 4; ++b) acc[a][b] = (f32x4){0.f, 0.f, 0.f, 0.f};

    for (int kt = 0; kt < KT_PER_JT; ++kt) {
      const int v = jt * KT_PER_JT + kt;
      // wait: stage(v) complete; stage(v+1)'s 4 loads may stay in flight.
      if (v < VTOT - 1) {
        asm volatile("s_waitcnt vmcnt(4)" ::: "memory");
      } else {
        asm volatile("s_waitcnt vmcnt(0)" ::: "memory");
      }
      __builtin_amdgcn_s_barrier();
      __builtin_amdgcn_sched_barrier(0);

      const char* tA = (const char*)&lds[bcur][0][0];
      const char* tB = (const char*)&lds[bcur][1][0];
      bf16x8 af[8], bfr[4];
#pragma unroll
      for (int mf = 0; mf < 4; ++mf)
        af[mf] = *(const bf16x8*)(tA + rdA + mf * 1024);
#pragma unroll
      for (int nf = 0; nf < 4; ++nf)
        bfr[nf] = *(const bf16x8*)(tB + rdB + nf * 1024);

      // prefetch K-tile v+2 into buffer (bcur+2)%3
      const int bstage = (bcur == 0) ? 2 : bcur - 1;
      if (v + 2 < VTOT) STAGE(v + 2, bstage);

      __builtin_amdgcn_s_setprio(1);
#pragma unroll
      for (int mf = 0; mf < 4; ++mf)
#pragma unroll
        for (int nf = 0; nf < 4; ++nf)
          acc[mf][nf] = __builtin_amdgcn_mfma_f32_16x16x32_bf16(
              af[mf], bfr[nf], acc[mf][nf], 0, 0, 0);
      __builtin_amdgcn_s_setprio(0);

#pragma unroll
      for (int mf = 4; mf < 8; ++mf)
        af[mf] = *(const bf16x8*)(tA + rdA + mf * 1024);

      __builtin_amdgcn_s_setprio(1);
#pragma unroll
      for (int mf = 4; mf < 8; ++mf)
#pragma unroll
        for (int nf = 0; nf < 4; ++nf)
          acc[mf][nf] = __builtin_amdgcn_mfma_f32_16x16x32_bf16(
              af[mf], bfr[nf], acc[mf][nf], 0, 0, 0);
      __builtin_amdgcn_s_setprio(0);

      bcur = (bcur == 2) ? 0 : bcur + 1;
    }

    // ---- epilogue: online LSE update for this j-tile (overlaps in-flight
    // prefetch loads; no vmcnt drain here).
    // acc[mf][nf][rg]: j = jbase + wr*128 + mf*16 + hi*4 + rg
    //                  i = r0 + wn*64 + nf*16 + lo
    {
      const int jb2 = c0 + jt * BNJ + wr * 128;
#pragma unroll
      for (int nf = 0; nf < 4; ++nf) {
        const int ig = r0 + wn * 64 + nf * 16 + lo;
        const int dg = ig - jb2;  // diagonal when dg == mf*16+hi*4+rg
        float vals[32];
        float tmax = -3.0e38f;
#pragma unroll
        for (int mf = 0; mf < 8; ++mf) {
#pragma unroll
          for (int rg = 0; rg < 4; ++rg) {
            const int jloc = mf * 16 + hi * 4 + rg;
            float vv = (dg == jloc) ? -1.0e9f : acc[mf][nf][rg] * scl;
            vals[mf * 4 + rg] = vv;
            tmax = fmaxf(tmax, vv);
          }
        }
        tmax = fmaxf(tmax, __shfl_xor(tmax, 16));
        tmax = fmaxf(tmax, __shfl_xor(tmax, 32));
        const float newm = fmaxf(m_st[nf], tmax);
        float ssum = 0.f;
#pragma unroll
        for (int q = 0; q < 32; ++q) ssum += exp2f(vals[q] - newm);
        ssum += __shfl_xor(ssum, 16);
        ssum += __shfl_xor(ssum, 32);
        l_st[nf] = l_st[nf] * exp2f(m_st[nf] - newm) + ssum;
        m_st[nf] = newm;
      }
    }
  }

  if (hi == 0) {
    const int p = blockIdx.y * 2 + wr;
#pragma unroll
    for (int nf = 0; nf < 4; ++nf) {
      const int ig = r0 + wn * 64 + nf * 16 + lo;
      part_m[(size_t)p * NN + ig] = m_st[nf];
      part_l[(size_t)p * NN + ig] = l_st[nf];
    }
  }
}

// ---------------- Kernel 3a: per-row combine -> per-block partial sums -------
__global__ __launch_bounds__(256) void finalize_part(
    const float* __restrict__ part_m, const float* __restrict__ part_l,
    const float* __restrict__ cross, const int* __restrict__ labels,
    float* __restrict__ bsum, float* __restrict__ bcnt, int B, int nparts) {
  const int NN = 2 * B;
  const int i = blockIdx.x * 256 + threadIdx.x;
  float sum = 0.f, cnt = 0.f;
  if (i < NN) {
    float M = -3.0e38f;
    for (int p = 0; p < nparts; ++p) M = fmaxf(M, part_m[(size_t)p * NN + i]);
    float L = 0.f;
    for (int p = 0; p < nparts; ++p)
      L += part_l[(size_t)p * NN + i] * exp2f(part_m[(size_t)p * NN + i] - M);
    const float lse = LN2 * (M + log2f(L));
    const float lab = (float)labels[i % B];
    sum = (lse - cross[i % B] * TEMP_INV) * lab;
    cnt = lab;
  }
#pragma unroll
  for (int off = 32; off; off >>= 1) {
    sum += __shfl_down(sum, off);
    cnt += __shfl_down(cnt, off);
  }
  __shared__ float rs[4], rc[4];
  const int wid = threadIdx.x >> 6, lane = threadIdx.x & 63;
  if (lane == 0) { rs[wid] = sum; rc[wid] = cnt; }
  __syncthreads();
  if (threadIdx.x == 0) {
    bsum[blockIdx.x] = rs[0] + rs[1] + rs[2] + rs[3];
    bcnt[blockIdx.x] = rc[0] + rc[1] + rc[2] + rc[3];
  }
}

// ---------------- Kernel 3b: final reduce ------------------------------------
__global__ __launch_bounds__(64) void finalize_final(
    const float* __restrict__ bsum, const float* __restrict__ bcnt,
    float* __restrict__ out, int nb) {
  const int t = threadIdx.x;
  float s = (t < nb) ? bsum[t] : 0.f;
  float c = (t < nb) ? bcnt[t] : 0.f;
#pragma unroll
  for (int off = 32; off; off >>= 1) {
    s += __shfl_down(s, off);
    c += __shfl_down(c, off);
  }
  if (t == 0) out[0] = (c > 0.f) ? s / c : 0.f;
}

extern "C" void kernel_launch(void* const* d_in, const int* in_sizes, int n_in,
                              void* d_out, int out_size, void* d_ws, size_t ws_size,
                              hipStream_t stream) {
  const float* A = (const float*)d_in[0];
  const float* P = (const float*)d_in[1];
  const int* labels = (const int*)d_in[2];
  float* out = (float*)d_out;
  const int B = in_sizes[2];
  const int D = in_sizes[0] / B;
  const int NN = 2 * B;

  char* ws = (char*)d_ws;
  ushort* F = (ushort*)ws;
  size_t off = (size_t)NN * D * sizeof(ushort);
  off = (off + 255) & ~(size_t)255;
  float* cross = (float*)(ws + off);
  off += (size_t)B * sizeof(float);
  off = (off + 255) & ~(size_t)255;
  float* part_m = (float*)(ws + off);
  off += (size_t)2 * NSPLIT * NN * sizeof(float);
  off = (off + 255) & ~(size_t)255;
  float* part_l = (float*)(ws + off);
  off += (size_t)2 * NSPLIT * NN * sizeof(float);
  off = (off + 255) & ~(size_t)255;
  float* bsum = (float*)(ws + off);
  off += 64 * sizeof(float);
  float* bcnt = (float*)(ws + off);

  norm_kernel<<<B, 256, 0, stream>>>(A, P, F, cross, B, D);
  dim3 g2(NN / BMI, NSPLIT);
  gram_lse_kernel<<<g2, 512, 0, stream>>>(F, part_m, part_l, NN, D);
  const int nb = (NN + 255) / 256;  // 32
  finalize_part<<<nb, 256, 0, stream>>>(part_m, part_l, cross, labels, bsum,
                                        bcnt, B, 2 * NSPLIT);
  finalize_final<<<1, 64, 0, stream>>>(bsum, bcnt, out, nb);
}

// Round 3
// 145.642 us; speedup vs baseline: 1.6491x; 1.0659x over previous
//
#include <hip/hip_runtime.h>
#include <hip/hip_bf16.h>

#define TEMP_INV (1.0f / 0.07f)
#define LOG2E 1.4426950408889634f
#define LN2 0.6931471805599453f
#define NSPLIT 8
#define CFIX 21.0f

typedef __attribute__((ext_vector_type(4))) float f32x4;
typedef __attribute__((ext_vector_type(8))) short bf16x8;

__device__ __forceinline__ ushort f2bf(float x) {
  union { float f; unsigned u; } v; v.f = x;
  unsigned r = (v.u + 0x7fffu + ((v.u >> 16) & 1u)) >> 16;
  return (ushort)r;
}

__device__ __forceinline__ void gload16(const ushort* g, ushort* l) {
  __builtin_amdgcn_global_load_lds(
      (const __attribute__((address_space(1))) void*)g,
      (__attribute__((address_space(3))) void*)l, 16, 0, 0);
}

// ---------------- Kernel 1: L2-normalize rows, write bf16 feats, cross dot ----
__global__ __launch_bounds__(256) void norm_kernel(
    const float* __restrict__ A, const float* __restrict__ P,
    ushort* __restrict__ F, float* __restrict__ cross, int B, int D) {
  const int row = blockIdx.x;
  const int t = threadIdx.x;
  const float4* a4 = reinterpret_cast<const float4*>(A + (size_t)row * D);
  const float4* p4 = reinterpret_cast<const float4*>(P + (size_t)row * D);
  const int n4 = D >> 2;
  float sa = 0.f, sp = 0.f, sx = 0.f;
  for (int i = t; i < n4; i += 256) {
    float4 av = a4[i], pv = p4[i];
    sa += av.x * av.x + av.y * av.y + av.z * av.z + av.w * av.w;
    sp += pv.x * pv.x + pv.y * pv.y + pv.z * pv.z + pv.w * pv.w;
    sx += av.x * pv.x + av.y * pv.y + av.z * pv.z + av.w * pv.w;
  }
#pragma unroll
  for (int off = 32; off; off >>= 1) {
    sa += __shfl_down(sa, off);
    sp += __shfl_down(sp, off);
    sx += __shfl_down(sx, off);
  }
  __shared__ float red[3][4];
  const int wid = t >> 6, lane = t & 63;
  if (lane == 0) { red[0][wid] = sa; red[1][wid] = sp; red[2][wid] = sx; }
  __syncthreads();
  sa = red[0][0] + red[0][1] + red[0][2] + red[0][3];
  sp = red[1][0] + red[1][1] + red[1][2] + red[1][3];
  sx = red[2][0] + red[2][1] + red[2][2] + red[2][3];
  const float ia = rsqrtf(sa), ip = rsqrtf(sp);
  ushort* fa = F + (size_t)row * D;
  ushort* fp = F + (size_t)(B + row) * D;
  for (int i = t; i < n4; i += 256) {
    float4 av = a4[i], pv = p4[i];
    ushort4 oa, op;
    oa.x = f2bf(av.x * ia); oa.y = f2bf(av.y * ia);
    oa.z = f2bf(av.z * ia); oa.w = f2bf(av.w * ia);
    op.x = f2bf(pv.x * ip); op.y = f2bf(pv.y * ip);
    op.z = f2bf(pv.z * ip); op.w = f2bf(pv.w * ip);
    reinterpret_cast<ushort4*>(fa)[i] = oa;
    reinterpret_cast<ushort4*>(fp)[i] = op;
  }
  if (t == 0) cross[row] = sx * ia * ip;
}

// ---------------- Kernel 2: fused Gram + fixed-max partial sums --------------
// 256x256 tile, BK=64 (2 k-half regions of 256x32), dbuf LDS = 8 x 16KB
// regions, 8-phase schedule w/ counted vmcnt(4) at P4/P8 only.
// Region layout (256x32 bf16, 16KB): paired rows, XOR-swizzled 16B chunks
// (verified conflict-free in R1/R2): elem (trow,k): lrow=trow>>1;
// cu=(trow&1)*4+(k>>3); c=cu^(lrow&7); byte=lrow*128+c*16+(k&7)*2.
#define BMI 256
#define BNJ 256
#define NJT 4  /* (NN/NSPLIT)/BNJ */
#define KT 16  /* D/64 */
#define VT (NJT * KT)

__global__ __launch_bounds__(512, 2) void gram_lse_kernel(
    const ushort* __restrict__ F, float* __restrict__ part_l, int NN, int D) {
  __shared__ ushort lds[2][2][2][8192];  // [buf][A=0/B=1][khalf][16KB region]
  const int r0 = blockIdx.x * BMI;            // i rows (B operand, N side)
  const int c0 = blockIdx.y * (NN / NSPLIT);  // j chunk base (A operand, M)
  const int t = threadIdx.x;
  const int lane = t & 63, w = t >> 6;
  const int lo = lane & 15, hi = lane >> 4;
  const int wr = w >> 2, wn = w & 3;  // wr: j-half(128), wn: i-quarter(64)

  // staging map (per thread): segments w and w+8 of each region
  const int l3 = lane >> 3, l7 = lane & 7;
  const int cu = l7 ^ l3;
  const int sub = cu >> 2, kc = cu & 3;
  const int trow0 = w * 16 + l3 * 2 + sub;
  const int trow1 = (w + 8) * 16 + l3 * 2 + sub;
  const ushort* baseA0 = F + (size_t)(c0 + trow0) * D + kc * 8;
  const ushort* baseA1 = F + (size_t)(c0 + trow1) * D + kc * 8;
  const ushort* baseB0 = F + (size_t)(r0 + trow0) * D + kc * 8;
  const ushort* baseB1 = F + (size_t)(r0 + trow1) * D + kc * 8;
  const int dst0 = w * 512, dst1 = (w + 8) * 512;  // ushort offsets (uniform)
  const size_t strideJ = (size_t)BNJ * D;

  // fragment read base (bytes within a region)
  const int cA = (((lo & 1) << 2) | hi) ^ (lo >> 1);
  const int rdBase = (lo >> 1) * 128 + cA * 16;

#define STAGE_A(T, KS, BUF)                                              \
  do {                                                                   \
    int c_ = (T); if (c_ > VT - 1) c_ = VT - 1;                          \
    const size_t o_ = (size_t)(c_ >> 4) * strideJ +                      \
                      (size_t)((c_ & 15) * 64 + (KS) * 32);              \
    gload16(baseA0 + o_, &lds[BUF][0][KS][dst0]);                        \
    gload16(baseA1 + o_, &lds[BUF][0][KS][dst1]);                        \
  } while (0)
#define STAGE_B(T, KS, BUF)                                              \
  do {                                                                   \
    int c_ = (T); if (c_ > VT - 1) c_ = VT - 1;                          \
    const size_t o_ = (size_t)((c_ & 15) * 64 + (KS) * 32);              \
    gload16(baseB0 + o_, &lds[BUF][1][KS][dst0]);                        \
    gload16(baseB1 + o_, &lds[BUF][1][KS][dst1]);                        \
  } while (0)

  f32x4 acc[8][4];
  bf16x8 bfr[4];
  float l_acc[4] = {0.f, 0.f, 0.f, 0.f};
  const float scl = LOG2E * TEMP_INV;

#define PHASE(BUF, MH, KS, READB, STAGE_STMT, WAIT4)                          \
  do {                                                                        \
    const char* RA_ = (const char*)&lds[BUF][0][KS][0];                       \
    const char* RB_ = (const char*)&lds[BUF][1][KS][0];                       \
    if (READB) {                                                              \
      _Pragma("unroll") for (int nf = 0; nf < 4; ++nf)                        \
          bfr[nf] = *(const bf16x8*)(RB_ + wn * 4096 + nf * 1024 + rdBase);   \
    }                                                                         \
    bf16x8 af[4];                                                             \
    _Pragma("unroll") for (int m = 0; m < 4; ++m)                             \
        af[m] = *(const bf16x8*)(RA_ + wr * 8192 + ((MH)*4 + m) * 1024 +      \
                                 rdBase);                                     \
    STAGE_STMT;                                                               \
    if (WAIT4) asm volatile("s_waitcnt vmcnt(4)" ::: "memory");               \
    asm volatile("" ::: "memory");                                            \
    __builtin_amdgcn_s_barrier();                                             \
    asm volatile("" ::: "memory");                                            \
    __builtin_amdgcn_s_setprio(1);                                            \
    _Pragma("unroll") for (int m = 0; m < 4; ++m)                             \
      _Pragma("unroll") for (int nf = 0; nf < 4; ++nf)                        \
          acc[(MH)*4 + m][nf] = __builtin_amdgcn_mfma_f32_16x16x32_bf16(      \
              af[m], bfr[nf], acc[(MH)*4 + m][nf], 0, 0, 0);                  \
    __builtin_amdgcn_s_setprio(0);                                            \
    asm volatile("" ::: "memory");                                            \
    __builtin_amdgcn_s_barrier();                                             \
    asm volatile("" ::: "memory");                                            \
  } while (0)

  // prologue: 7 half-tiles (A1k1 is staged by iter0's P1)
  STAGE_A(0, 0, 0); STAGE_B(0, 0, 0);
  STAGE_A(0, 1, 0); STAGE_B(0, 1, 0);
  STAGE_A(1, 0, 1); STAGE_B(1, 0, 1);
  STAGE_B(1, 1, 1);
  asm volatile("s_waitcnt vmcnt(6)" ::: "memory");
  __builtin_amdgcn_s_barrier();
  asm volatile("" ::: "memory");

  for (int jt = 0; jt < NJT; ++jt) {
#pragma unroll
    for (int a = 0; a < 8; ++a)
#pragma unroll
      for (int b = 0; b < 4; ++b) acc[a][b] = (f32x4){0.f, 0.f, 0.f, 0.f};

    for (int it = 0; it < 8; ++it) {
      const int tt = jt * 16 + it * 2;  // even tile; buf0=0, buf1=1
      PHASE(0, 0, 0, true,  STAGE_A(tt + 1, 1, 1), false);  // P1
      PHASE(0, 1, 0, false, STAGE_B(tt + 2, 0, 0), false);  // P2
      PHASE(0, 0, 1, true,  STAGE_A(tt + 2, 0, 0), false);  // P3
      PHASE(0, 1, 1, false, STAGE_B(tt + 2, 1, 0), true);   // P4 vmcnt(4)
      PHASE(1, 0, 0, true,  STAGE_A(tt + 2, 1, 0), false);  // P5
      PHASE(1, 1, 0, false, STAGE_B(tt + 3, 0, 1), false);  // P6
      PHASE(1, 0, 1, true,  STAGE_A(tt + 3, 0, 1), false);  // P7
      PHASE(1, 1, 1, false, STAGE_B(tt + 3, 1, 1), true);   // P8 vmcnt(4)
    }

    // epilogue: fixed-max exp accumulate (no LDS, overlaps in-flight loads)
    // acc[mf][nf][rg]: j = c0 + jt*256 + wr*128 + mf*16 + hi*4 + rg
    //                  i = r0 + wn*64 + nf*16 + lo
    {
      const int jb2 = c0 + jt * 256 + wr * 128;
#pragma unroll
      for (int nf = 0; nf < 4; ++nf) {
        const int dg = (r0 + wn * 64 + nf * 16 + lo) - jb2;
        float s = 0.f;
#pragma unroll
        for (int mf = 0; mf < 8; ++mf)
#pragma unroll
          for (int rg = 0; rg < 4; ++rg) {
            const int jloc = mf * 16 + hi * 4 + rg;
            const float e = exp2f(acc[mf][nf][rg] * scl - CFIX);
            s += (dg == jloc) ? 0.f : e;
          }
        l_acc[nf] += s;
      }
    }
  }

  // drain remaining (clamped) stage loads before kernel end / final writes
  asm volatile("s_waitcnt vmcnt(0)" ::: "memory");

#pragma unroll
  for (int nf = 0; nf < 4; ++nf) {
    float v = l_acc[nf];
    v += __shfl_xor(v, 16);
    v += __shfl_xor(v, 32);
    if (hi == 0) {
      const int ig = r0 + wn * 64 + nf * 16 + lo;
      part_l[(size_t)(blockIdx.y * 2 + wr) * NN + ig] = v;
    }
  }
#undef PHASE
#undef STAGE_A
#undef STAGE_B
}

// ---------------- Kernel 3a: per-row combine -> per-block partial sums -------
__global__ __launch_bounds__(256) void finalize_part(
    const float* __restrict__ part_l, const float* __restrict__ cross,
    const int* __restrict__ labels, float* __restrict__ bsum,
    float* __restrict__ bcnt, int B, int nparts) {
  const int NN = 2 * B;
  const int i = blockIdx.x * 256 + threadIdx.x;
  float sum = 0.f, cnt = 0.f;
  if (i < NN) {
    float L = 0.f;
    for (int p = 0; p < nparts; ++p) L += part_l[(size_t)p * NN + i];
    const float lse = LN2 * (CFIX + log2f(L));
    const float lab = (float)labels[i % B];
    sum = (lse - cross[i % B] * TEMP_INV) * lab;
    cnt = lab;
  }
#pragma unroll
  for (int off = 32; off; off >>= 1) {
    sum += __shfl_down(sum, off);
    cnt += __shfl_down(cnt, off);
  }
  __shared__ float rs[4], rc[4];
  const int wid = threadIdx.x >> 6, lane = threadIdx.x & 63;
  if (lane == 0) { rs[wid] = sum; rc[wid] = cnt; }
  __syncthreads();
  if (threadIdx.x == 0) {
    bsum[blockIdx.x] = rs[0] + rs[1] + rs[2] + rs[3];
    bcnt[blockIdx.x] = rc[0] + rc[1] + rc[2] + rc[3];
  }
}

// ---------------- Kernel 3b: final reduce ------------------------------------
__global__ __launch_bounds__(64) void finalize_final(
    const float* __restrict__ bsum, const float* __restrict__ bcnt,
    float* __restrict__ out, int nb) {
  const int t = threadIdx.x;
  float s = (t < nb) ? bsum[t] : 0.f;
  float c = (t < nb) ? bcnt[t] : 0.f;
#pragma unroll
  for (int off = 32; off; off >>= 1) {
    s += __shfl_down(s, off);
    c += __shfl_down(c, off);
  }
  if (t == 0) out[0] = (c > 0.f) ? s / c : 0.f;
}

extern "C" void kernel_launch(void* const* d_in, const int* in_sizes, int n_in,
                              void* d_out, int out_size, void* d_ws, size_t ws_size,
                              hipStream_t stream) {
  const float* A = (const float*)d_in[0];
  const float* P = (const float*)d_in[1];
  const int* labels = (const int*)d_in[2];
  float* out = (float*)d_out;
  const int B = in_sizes[2];
  const int D = in_sizes[0] / B;
  const int NN = 2 * B;

  char* ws = (char*)d_ws;
  ushort* F = (ushort*)ws;
  size_t off = (size_t)NN * D * sizeof(ushort);
  off = (off + 255) & ~(size_t)255;
  float* cross = (float*)(ws + off);
  off += (size_t)B * sizeof(float);
  off = (off + 255) & ~(size_t)255;
  float* part_l = (float*)(ws + off);
  off += (size_t)2 * NSPLIT * NN * sizeof(float);
  off = (off + 255) & ~(size_t)255;
  float* bsum = (float*)(ws + off);
  off += 64 * sizeof(float);
  float* bcnt = (float*)(ws + off);

  norm_kernel<<<B, 256, 0, stream>>>(A, P, F, cross, B, D);
  dim3 g2(NN / BMI, NSPLIT);
  gram_lse_kernel<<<g2, 512, 0, stream>>>(F, part_l, NN, D);
  const int nb = (NN + 255) / 256;  // 32
  finalize_part<<<nb, 256, 0, stream>>>(part_l, cross, labels, bsum, bcnt, B,
                                        2 * NSPLIT);
  finalize_final<<<1, 64, 0, stream>>>(bsum, bcnt, out, nb);
}